// Round 6
// baseline (1012.753 us; speedup 1.0000x reference)
//
#include <hip/hip_runtime.h>
#include <math.h>

#define H_ 128
static constexpr int NG_ = 20000, NP_ = 3000, B_ = 2;
static constexpr int EGG_ = 200000, ETG_ = 200000, EGP_ = 200000, EPP_ = 100000;
static constexpr float TAU_ = 0.5f;
static constexpr float RSQRTH_ = 0.088388347648318447f; // 1/sqrt(128)

// ---------------- batched CSR build ----------------
struct CsrDesc {
  const int* dst;
  int E, N;
  int* cnt;
  int* cur;
  int* off;
  int* bkt;
};
struct CsrPack { CsrDesc c[5]; };

__global__ void hist_all_k(CsrPack p) {
  CsrDesc d = p.c[blockIdx.y];
  int i = blockIdx.x * 256 + threadIdx.x;
  if (i < d.E) atomicAdd(&d.cnt[d.dst[i]], 1);
}

__global__ void scatter_all_k(CsrPack p) {
  CsrDesc d = p.c[blockIdx.y];
  int i = blockIdx.x * 256 + threadIdx.x;
  if (i < d.E) {
    int t = d.dst[i];
    int pos = atomicAdd(&d.cur[t], 1);
    d.bkt[d.off[t] + pos] = i;
  }
}

__global__ void exscan_all_k(CsrPack p) {
  CsrDesc d = p.c[blockIdx.x];
  const int n = d.N;
  const int* cnt = d.cnt;
  int* off = d.off;
  __shared__ int sh[256];
  const int tid = threadIdx.x;
  if (tid == 0) off[0] = 0;
  int run = 0;
  for (int base = 0; base < n; base += 4096) {
    int loc[16];
    int s = 0;
#pragma unroll
    for (int j = 0; j < 16; ++j) {
      int i = base + tid * 16 + j;
      loc[j] = (i < n) ? cnt[i] : 0;
      s += loc[j];
    }
    sh[tid] = s;
    __syncthreads();
    for (int st = 1; st < 256; st <<= 1) {
      int v = (tid >= st) ? sh[tid - st] : 0;
      __syncthreads();
      sh[tid] += v;
      __syncthreads();
    }
    int acc = run + ((tid > 0) ? sh[tid - 1] : 0);
    int tot = sh[255];
    __syncthreads();
#pragma unroll
    for (int j = 0; j < 16; ++j) {
      int i = base + tid * 16 + j;
      acc += loc[j];
      if (i < n) off[i + 1] = acc;
    }
    run += tot;
  }
}

// ---------------- multi-op GEMM ----------------
// X-tile (ROWS x 128) staged once in LDS; W streamed from global (L2-hot).
// 16-lane column groups: each thread owns 8 output cols; a wave's W-load
// instruction touches only 256 distinct bytes (broadcast across ty-groups).
// VGPR kept <=64 (launch_bounds min-8-waves/EU) so 8 waves/SIMD hide latency.
// Up to 4 sequential ops: Y = act(Cur @ W + bias); TOLDS keeps result in LDS.
static constexpr int GF_RELU = 1, GF_TOLDS = 2;
struct GOp { const float* W; const float* bias; float* Y; int flags; };
struct GPack { GOp o[4]; };

template <int NOPS, int ROWS>
__global__ __launch_bounds__(256, 8) void gemmN_k(const float* __restrict__ X, GPack p, int R) {
  constexpr int RPR = ROWS / 16;  // rows per thread
  __shared__ float Xl[ROWS][132];
  const int t = threadIdx.x;
  const int tx = t & 15, ty = t >> 4;  // 16 col-groups x 16 row-groups
  const int r0 = blockIdx.x * ROWS;
#pragma unroll
  for (int it = 0; it < ROWS / 8; ++it) {
    int idx = t + 256 * it;
    int row = idx >> 5;
    int kq = idx & 31;
    int gr = r0 + row;
    float4 v = make_float4(0.f, 0.f, 0.f, 0.f);
    if (gr < R) v = *(const float4*)&X[(size_t)gr * 128 + kq * 4];
    *(float4*)&Xl[row][kq * 4] = v;
  }
  __syncthreads();
#pragma unroll
  for (int op = 0; op < NOPS; ++op) {
    const float4* __restrict__ Wv = (const float4*)p.o[op].W;
    float acc[RPR][8];
#pragma unroll
    for (int i = 0; i < RPR; ++i)
#pragma unroll
      for (int c = 0; c < 8; ++c) acc[i][c] = 0.f;
#pragma unroll 2
    for (int k = 0; k < 128; k += 4) {
      float4 w[8];  // w[2*kk+h]: W[k+kk][tx*8+4h .. +3]
#pragma unroll
      for (int kk = 0; kk < 4; ++kk) {
        w[2 * kk] = Wv[(k + kk) * 32 + tx * 2];
        w[2 * kk + 1] = Wv[(k + kk) * 32 + tx * 2 + 1];
      }
#pragma unroll
      for (int i = 0; i < RPR; ++i) {
        float4 xv = *(const float4*)&Xl[ty * RPR + i][k];
        const float xk[4] = {xv.x, xv.y, xv.z, xv.w};
#pragma unroll
        for (int kk = 0; kk < 4; ++kk) {
          acc[i][0] += xk[kk] * w[2 * kk].x;
          acc[i][1] += xk[kk] * w[2 * kk].y;
          acc[i][2] += xk[kk] * w[2 * kk].z;
          acc[i][3] += xk[kk] * w[2 * kk].w;
          acc[i][4] += xk[kk] * w[2 * kk + 1].x;
          acc[i][5] += xk[kk] * w[2 * kk + 1].y;
          acc[i][6] += xk[kk] * w[2 * kk + 1].z;
          acc[i][7] += xk[kk] * w[2 * kk + 1].w;
        }
      }
    }
    float4 b0 = make_float4(0.f, 0.f, 0.f, 0.f), b1 = b0;
    if (p.o[op].bias) {
      b0 = *(const float4*)&p.o[op].bias[tx * 8];
      b1 = *(const float4*)&p.o[op].bias[tx * 8 + 4];
    }
    const bool relu = (p.o[op].flags & GF_RELU) != 0;
#pragma unroll
    for (int i = 0; i < RPR; ++i) {
      float o[8];
      o[0] = acc[i][0] + b0.x; o[1] = acc[i][1] + b0.y;
      o[2] = acc[i][2] + b0.z; o[3] = acc[i][3] + b0.w;
      o[4] = acc[i][4] + b1.x; o[5] = acc[i][5] + b1.y;
      o[6] = acc[i][6] + b1.z; o[7] = acc[i][7] + b1.w;
      if (relu) {
#pragma unroll
        for (int c = 0; c < 8; ++c) o[c] = fmaxf(o[c], 0.f);
      }
#pragma unroll
      for (int c = 0; c < 8; ++c) acc[i][c] = o[c];
    }
    if (p.o[op].flags & GF_TOLDS) {
      __syncthreads();  // all reads of old tile done
#pragma unroll
      for (int i = 0; i < RPR; ++i) {
        int row = ty * RPR + i;
        *(float4*)&Xl[row][tx * 8] = make_float4(acc[i][0], acc[i][1], acc[i][2], acc[i][3]);
        *(float4*)&Xl[row][tx * 8 + 4] = make_float4(acc[i][4], acc[i][5], acc[i][6], acc[i][7]);
      }
      __syncthreads();
    } else {
      float* __restrict__ Y = p.o[op].Y;
#pragma unroll
      for (int i = 0; i < RPR; ++i) {
        int gr = r0 + ty * RPR + i;
        if (gr < R) {
          *(float4*)&Y[(size_t)gr * 128 + tx * 8] =
              make_float4(acc[i][0], acc[i][1], acc[i][2], acc[i][3]);
          *(float4*)&Y[(size_t)gr * 128 + tx * 8 + 4] =
              make_float4(acc[i][4], acc[i][5], acc[i][6], acc[i][7]);
        }
      }
    }
  }
}

// ---------------- fused attention: score + top-k prune + compact + aggregate ----------------
// 256 threads = 4 waves; each wave owns one (batch,target). Per-wave LDS slices,
// wave lockstep orders phases (no __syncthreads).
template <int CAP>
__global__ __launch_bounds__(256) void attn_agg_k(
    const int* __restrict__ off, const int* __restrict__ bkt,
    const int* __restrict__ fidx, const float* __restrict__ ew,
    const float* __restrict__ Q, const float* __restrict__ K,
    const float* __restrict__ V, float* __restrict__ out,
    int nT, int nS, int topk) {
  __shared__ float s_sh[4][CAP];
  __shared__ int f_sh[4][CAP];
  __shared__ int e_sh[4][CAP];
  __shared__ int c_sh[4][CAP];
  __shared__ float q_sh[4][128];
  const int wv = threadIdx.x >> 6, lane = threadIdx.x & 63;
  const int t = blockIdx.x * 4 + wv, b = blockIdx.y;
  if (t >= nT) return;
  const int o0 = off[t];
  const int ne = min(off[t + 1] - o0, CAP);
  if (ne == 0) return;

  for (int i = lane; i < ne; i += 64) {
    int e = bkt[o0 + i];
    f_sh[wv][i] = fidx[e];
    e_sh[wv][i] = e;
    s_sh[wv][i] = ew[e];
  }
  *(float2*)&q_sh[wv][lane * 2] = *(const float2*)&Q[((size_t)b * nT + t) * 128 + lane * 2];

  // scores: 8 groups of 8 lanes -> 8 edges in flight
  const int g = lane >> 3, l = lane & 7;
  float4 q[4];
#pragma unroll
  for (int j = 0; j < 4; ++j) q[j] = *(const float4*)&q_sh[wv][(l + 8 * j) * 4];
  for (int i0 = 0; i0 < ne; i0 += 8) {
    int idx = i0 + g;
    bool val = idx < ne;
    int f = f_sh[wv][val ? idx : 0];
    const float4* kr = (const float4*)&K[((size_t)b * nS + f) * 128];
    float p = 0.f;
#pragma unroll
    for (int j = 0; j < 4; ++j) {
      float4 kv = kr[l + 8 * j];
      p += kv.x * q[j].x + kv.y * q[j].y + kv.z * q[j].z + kv.w * q[j].w;
    }
    p += __shfl_xor(p, 1);
    p += __shfl_xor(p, 2);
    p += __shfl_xor(p, 4);
    if (l == 0 && val) {
      float w = s_sh[wv][idx];  // edge weight (read before overwrite)
      s_sh[wv][idx] = 1.f / (1.f + expf(-p * RSQRTH_ * w));
    }
  }

  // prune: rank = #{j: s_j > s_i or (s_j == s_i and e_j < e_i)}
  float keep[(CAP + 63) / 64];
#pragma unroll
  for (int c = 0; c * 64 < CAP; ++c) {
    int i = lane + c * 64;
    float r = 0.f;
    if (i < ne) {
      float si = s_sh[wv][i];
      int ei = e_sh[wv][i];
      int cnt = 0;
      for (int j = 0; j < ne; ++j) {
        float sj = s_sh[wv][j];
        cnt += (sj > si) || (sj == si && e_sh[wv][j] < ei);
      }
      r = (cnt < topk && si > TAU_) ? si : 0.f;
    }
    keep[c] = r;
  }
#pragma unroll
  for (int c = 0; c * 64 < CAP; ++c) {
    int i = lane + c * 64;
    if (i < ne) s_sh[wv][i] = keep[c];
  }

  // ballot-compact selected edge slots
  int nsel = 0;
  for (int c = 0; c * 64 < ne; ++c) {
    int i = c * 64 + lane;
    bool sel = (i < ne) && (s_sh[wv][i] != 0.f);
    unsigned long long m = __ballot(sel);
    int pos = __popcll(m & ((1ull << lane) - 1ull));
    if (sel) c_sh[wv][nsel + pos] = i;
    nsel += __popcll(m);
  }

  // aggregate over compact list, 2x unrolled paired loads
  size_t orow = ((size_t)b * nT + t) * 128 + lane * 2;
  float2 acc = *(float2*)&out[orow];
  int j = 0;
  for (; j + 2 <= nsel; j += 2) {
    int i0 = c_sh[wv][j], i1 = c_sh[wv][j + 1];
    float w0 = s_sh[wv][i0], w1 = s_sh[wv][i1];
    float2 v0 = *(const float2*)&V[((size_t)b * nS + f_sh[wv][i0]) * 128 + lane * 2];
    float2 v1 = *(const float2*)&V[((size_t)b * nS + f_sh[wv][i1]) * 128 + lane * 2];
    acc.x += w0 * v0.x + w1 * v1.x;
    acc.y += w0 * v0.y + w1 * v1.y;
  }
  if (j < nsel) {
    int i0 = c_sh[wv][j];
    float w0 = s_sh[wv][i0];
    float2 v0 = *(const float2*)&V[((size_t)b * nS + f_sh[wv][i0]) * 128 + lane * 2];
    acc.x += w0 * v0.x;
    acc.y += w0 * v0.y;
  }
  *(float2*)&out[orow] = acc;
}

// ---------------- plain weighted aggregation (fixed edge weights) ----------------
template <int CAP>
__global__ __launch_bounds__(256) void wagg_k(
    const int* __restrict__ off, const int* __restrict__ bkt,
    const int* __restrict__ fidx, const float* __restrict__ ew,
    const float* __restrict__ V, float* __restrict__ out, int nT, int nS) {
  __shared__ float s_sh[4][CAP];
  __shared__ int f_sh[4][CAP];
  const int wv = threadIdx.x >> 6, lane = threadIdx.x & 63;
  const int t = blockIdx.x * 4 + wv, b = blockIdx.y;
  if (t >= nT) return;
  const int o0 = off[t];
  const int ne = min(off[t + 1] - o0, CAP);
  if (ne == 0) return;
  for (int i = lane; i < ne; i += 64) {
    int e = bkt[o0 + i];
    f_sh[wv][i] = fidx[e];
    s_sh[wv][i] = ew[e];
  }
  size_t orow = ((size_t)b * nT + t) * 128 + lane * 2;
  float2 acc = *(float2*)&out[orow];
  int i = 0;
  for (; i + 2 <= ne; i += 2) {
    float w0 = s_sh[wv][i], w1 = s_sh[wv][i + 1];
    float2 v0 = *(const float2*)&V[((size_t)b * nS + f_sh[wv][i]) * 128 + lane * 2];
    float2 v1 = *(const float2*)&V[((size_t)b * nS + f_sh[wv][i + 1]) * 128 + lane * 2];
    acc.x += w0 * v0.x + w1 * v1.x;
    acc.y += w0 * v0.y + w1 * v1.y;
  }
  if (i < ne) {
    float w0 = s_sh[wv][i];
    float2 v0 = *(const float2*)&V[((size_t)b * nS + f_sh[wv][i]) * 128 + lane * 2];
    acc.x += w0 * v0.x;
    acc.y += w0 * v0.y;
  }
  *(float2*)&out[orow] = acc;
}

// ---------------- host ----------------
extern "C" void kernel_launch(void* const* d_in, const int* in_sizes, int n_in, void* d_out,
                              int out_size, void* d_ws, size_t ws_size, hipStream_t stream) {
  const float* gene = (const float*)d_in[0];
  const float* path = (const float*)d_in[1];
  const float* gg_w = (const float*)d_in[2];
  const float* tg_w = (const float*)d_in[3];
  const float* gp_w = (const float*)d_in[4];
  const float* pp_w = (const float*)d_in[5];
  const int* gg_src = (const int*)d_in[6];
  const int* gg_dst = (const int*)d_in[7];
  const int* tg_src = (const int*)d_in[8];
  const int* tg_dst = (const int*)d_in[9];
  const int* gp_src = (const int*)d_in[10];
  const int* gp_dst = (const int*)d_in[11];
  const int* pp_src = (const int*)d_in[12];
  const int* pp_dst = (const int*)d_in[13];
  const float* mgg_w1 = (const float*)d_in[14];
  const float* mgg_b1 = (const float*)d_in[15];
  const float* mgg_w2 = (const float*)d_in[16];
  const float* mgg_b2 = (const float*)d_in[17];
  const float* mgp_w1 = (const float*)d_in[18];
  const float* mgp_b1 = (const float*)d_in[19];
  const float* mgp_w2 = (const float*)d_in[20];
  const float* mgp_b2 = (const float*)d_in[21];
  const float* mpp_w1 = (const float*)d_in[22];
  const float* mpp_b1 = (const float*)d_in[23];
  const float* mpp_w2 = (const float*)d_in[24];
  const float* mpp_b2 = (const float*)d_in[25];
  const float* mpg_w1 = (const float*)d_in[26];
  const float* mpg_b1 = (const float*)d_in[27];
  const float* mpg_w2 = (const float*)d_in[28];
  const float* mpg_b2 = (const float*)d_in[29];
  const float* w_gg = (const float*)d_in[30];
  const float* w_pp = (const float*)d_in[31];
  const float* w_pg = (const float*)d_in[32];
  const float* tg_q = (const float*)d_in[33];
  const float* tg_k = (const float*)d_in[34];
  const float* tg_v_tf = (const float*)d_in[35];
  const float* tg_v_gene = (const float*)d_in[36];
  const float* gp_q = (const float*)d_in[37];
  const float* gp_k = (const float*)d_in[38];
  const float* gp_v = (const float*)d_in[39];

  float* out_final = (float*)d_out;                       // [B,NG,H]
  float* out_h3 = (float*)d_out + (size_t)B_ * NG_ * H_;  // [B,NP,H]

  const size_t BNGH = (size_t)B_ * NG_ * H_;
  const size_t BNPH = (size_t)B_ * NP_ * H_;

  char* wp = (char*)d_ws;
  auto alloc = [&](size_t bytes) {
    void* p = (void*)wp;
    wp += (bytes + 255) & ~(size_t)255;
    return p;
  };
  float* G0 = (float*)alloc(BNGH * 4);  // h1
  float* G2 = (float*)alloc(BNGH * 4);  // Xw / q_gene / k_g
  float* G3 = (float*)alloc(BNGH * 4);  // k_tf / v_g
  float* G4 = (float*)alloc(BNGH * 4);  // v_tf
  float* G5 = (float*)alloc(BNGH * 4);  // h2
  float* P0 = (float*)alloc(BNPH * 4);  // q_p / Yw / Zw
  float* P2 = (float*)alloc(BNPH * 4);  // bar_h3
  const int NCNT = 3 * NG_ + 2 * NP_;
  int* cntbuf = (int*)alloc((size_t)NCNT * 2 * 4);
  int* cnt_gg = cntbuf;
  int* cnt_tg = cnt_gg + NG_;
  int* cnt_gps = cnt_tg + NG_;
  int* cnt_gpd = cnt_gps + NG_;
  int* cnt_pp = cnt_gpd + NP_;
  int* cur0 = cntbuf + NCNT;
  int* cur_gg = cur0;
  int* cur_tg = cur_gg + NG_;
  int* cur_gps = cur_tg + NG_;
  int* cur_gpd = cur_gps + NG_;
  int* cur_pp = cur_gpd + NP_;
  int* off_gg = (int*)alloc((size_t)(NG_ + 1) * 4);
  int* off_tg = (int*)alloc((size_t)(NG_ + 1) * 4);
  int* off_gps = (int*)alloc((size_t)(NG_ + 1) * 4);
  int* off_gpd = (int*)alloc((size_t)(NP_ + 1) * 4);
  int* off_pp = (int*)alloc((size_t)(NP_ + 1) * 4);
  int* bkt_gg = (int*)alloc((size_t)EGG_ * 4);
  int* bkt_tg = (int*)alloc((size_t)ETG_ * 4);
  int* bkt_gps = (int*)alloc((size_t)EGP_ * 4);
  int* bkt_gpd = (int*)alloc((size_t)EGP_ * 4);
  int* bkt_pp = (int*)alloc((size_t)EPP_ * 4);

  hipMemsetAsync(cntbuf, 0, (size_t)NCNT * 2 * 4, stream);
  CsrPack pk;
  pk.c[0] = {gg_dst, EGG_, NG_, cnt_gg, cur_gg, off_gg, bkt_gg};
  pk.c[1] = {tg_dst, ETG_, NG_, cnt_tg, cur_tg, off_tg, bkt_tg};
  pk.c[2] = {gp_src, EGP_, NG_, cnt_gps, cur_gps, off_gps, bkt_gps};
  pk.c[3] = {gp_dst, EGP_, NP_, cnt_gpd, cur_gpd, off_gpd, bkt_gpd};
  pk.c[4] = {pp_dst, EPP_, NP_, cnt_pp, cur_pp, off_pp, bkt_pp};
  hist_all_k<<<dim3((EGG_ + 255) / 256, 5), dim3(256), 0, stream>>>(pk);
  exscan_all_k<<<dim3(5), dim3(256), 0, stream>>>(pk);
  scatter_all_k<<<dim3((EGG_ + 255) / 256, 5), dim3(256), 0, stream>>>(pk);

  const int RG = B_ * NG_;  // 40000
  const int RP = B_ * NP_;  // 6000
  const dim3 gG((RG + 31) / 32), gP((RP + 15) / 16), blk(256);

  // ---- Layer 1: h1 = mlp_gg(gene) + scatter(gg_w * (gene@w_gg)[src]) ----
  {
    GPack p{};
    p.o[0] = {w_gg, nullptr, G2, 0};
    p.o[1] = {mgg_w1, mgg_b1, nullptr, GF_RELU | GF_TOLDS};
    p.o[2] = {mgg_w2, mgg_b2, G0, 0};
    gemmN_k<3, 32><<<gG, blk, 0, stream>>>(gene, p, RG);
  }
  wagg_k<128><<<dim3((NG_ + 3) / 4, B_), blk, 0, stream>>>(off_gg, bkt_gg, gg_src, gg_w, G2, G0,
                                                           NG_, NG_);
  // ---- Layer 2: TF->gene attention ----
  {
    GPack p{};
    p.o[0] = {tg_q, nullptr, G2, 0};
    p.o[1] = {tg_k, nullptr, G3, 0};
    p.o[2] = {tg_v_tf, nullptr, G4, 0};
    p.o[3] = {tg_v_gene, nullptr, G5, 0};
    gemmN_k<4, 32><<<gG, blk, 0, stream>>>(G0, p, RG);
  }
  attn_agg_k<128><<<dim3((NG_ + 3) / 4, B_), blk, 0, stream>>>(
      off_tg, bkt_tg, tg_src, tg_w, G2, G3, G4, G5, NG_, NG_, 16);
  // ---- Layer 3 projections + Layer 5 MLP (both read G5, merged) ----
  {
    GPack p{};
    p.o[0] = {gp_k, nullptr, G2, 0};
    p.o[1] = {gp_v, nullptr, G3, 0};
    p.o[2] = {mpg_w1, mpg_b1, nullptr, GF_RELU | GF_TOLDS};
    p.o[3] = {mpg_w2, mpg_b2, out_final, 0};  // final base; wagg adds later
    gemmN_k<4, 32><<<gG, blk, 0, stream>>>(G5, p, RG);
  }
  {
    GPack p{};
    p.o[0] = {gp_q, nullptr, P0, 0};
    p.o[1] = {mgp_w1, mgp_b1, nullptr, GF_RELU | GF_TOLDS};
    p.o[2] = {mgp_w2, mgp_b2, P2, 0};
    gemmN_k<3, 16><<<gP, blk, 0, stream>>>(path, p, RP);
  }
  attn_agg_k<256><<<dim3((NP_ + 3) / 4, B_), blk, 0, stream>>>(
      off_gpd, bkt_gpd, gp_src, gp_w, P0, G2, G3, P2, NP_, NG_, 32);
  // ---- Layer 4: pathway-pathway ----
  {
    GPack p{};
    p.o[0] = {w_pp, nullptr, P0, 0};
    p.o[1] = {mpp_w1, mpp_b1, nullptr, GF_RELU | GF_TOLDS};
    p.o[2] = {mpp_w2, mpp_b2, out_h3, 0};
    gemmN_k<3, 16><<<gP, blk, 0, stream>>>(P2, p, RP);
  }
  wagg_k<192><<<dim3((NP_ + 3) / 4, B_), blk, 0, stream>>>(off_pp, bkt_pp, pp_src, pp_w, P0,
                                                           out_h3, NP_, NP_);
  // ---- Layer 5: pathway->gene feedback ----
  {
    GPack p{};
    p.o[0] = {w_pg, nullptr, P0, 0};
    gemmN_k<1, 16><<<gP, blk, 0, stream>>>(out_h3, p, RP);
  }
  wagg_k<128><<<dim3((NG_ + 3) / 4, B_), blk, 0, stream>>>(off_gps, bkt_gps, gp_dst, gp_w, P0,
                                                           out_final, NG_, NP_);
  (void)in_sizes; (void)n_in; (void)out_size; (void)ws_size;
}

// Round 7
// 840.063 us; speedup vs baseline: 1.2056x; 1.2056x over previous
//
#include <hip/hip_runtime.h>
#include <math.h>

#define H_ 128
static constexpr int NG_ = 20000, NP_ = 3000, B_ = 2;
static constexpr int EGG_ = 200000, ETG_ = 200000, EGP_ = 200000, EPP_ = 100000;
static constexpr float TAU_ = 0.5f;
static constexpr float RSQRTH_ = 0.088388347648318447f; // 1/sqrt(128)

// ---------------- batched CSR build ----------------
struct CsrDesc {
  const int* dst;
  int E, N;
  int* cnt;
  int* cur;
  int* off;
  int* bkt;
};
struct CsrPack { CsrDesc c[5]; };

__global__ void hist_all_k(CsrPack p) {
  CsrDesc d = p.c[blockIdx.y];
  int i = blockIdx.x * 256 + threadIdx.x;
  if (i < d.E) atomicAdd(&d.cnt[d.dst[i]], 1);
}

__global__ void scatter_all_k(CsrPack p) {
  CsrDesc d = p.c[blockIdx.y];
  int i = blockIdx.x * 256 + threadIdx.x;
  if (i < d.E) {
    int t = d.dst[i];
    int pos = atomicAdd(&d.cur[t], 1);
    d.bkt[d.off[t] + pos] = i;
  }
}

__global__ void exscan_all_k(CsrPack p) {
  CsrDesc d = p.c[blockIdx.x];
  const int n = d.N;
  const int* cnt = d.cnt;
  int* off = d.off;
  __shared__ int sh[256];
  const int tid = threadIdx.x;
  if (tid == 0) off[0] = 0;
  int run = 0;
  for (int base = 0; base < n; base += 4096) {
    int loc[16];
    int s = 0;
#pragma unroll
    for (int j = 0; j < 16; ++j) {
      int i = base + tid * 16 + j;
      loc[j] = (i < n) ? cnt[i] : 0;
      s += loc[j];
    }
    sh[tid] = s;
    __syncthreads();
    for (int st = 1; st < 256; st <<= 1) {
      int v = (tid >= st) ? sh[tid - st] : 0;
      __syncthreads();
      sh[tid] += v;
      __syncthreads();
    }
    int acc = run + ((tid > 0) ? sh[tid - 1] : 0);
    int tot = sh[255];
    __syncthreads();
#pragma unroll
    for (int j = 0; j < 16; ++j) {
      int i = base + tid * 16 + j;
      acc += loc[j];
      if (i < n) off[i + 1] = acc;
    }
    run += tot;
  }
}

// ---------------- chained multi-op GEMM ----------------
// X-tile (ROWS x 128) staged in LDS; W streamed from global (L2-hot).
// Round-4 instruction mix (4 W-loads : 64 FMA per 4-k chunk, tx owns 4 cols);
// independent ops run as blockIdx.y chains for full-grid occupancy. A chain
// of 2 ops implements an MLP: first op writes ReLU hidden to LDS (TOLDS),
// second consumes it. VGPR <=64 via launch_bounds(256,8).
static constexpr int GF_RELU = 1, GF_TOLDS = 2;
struct GOp { const float* W; const float* bias; float* Y; int flags; int chain; };
struct GPack { GOp o[4]; };

template <int NOPS, int ROWS>
__global__ __launch_bounds__(256, 8) void gemm_k(const float* __restrict__ X, GPack p, int R) {
  constexpr int RPR = ROWS / 8;  // rows per thread (8 row-groups)
  __shared__ float Xl[ROWS][132];
  const int t = threadIdx.x;
  const int tx = t & 31, ty = t >> 5;
  const int r0 = blockIdx.x * ROWS;
  const int ch = (int)blockIdx.y;
#pragma unroll
  for (int it = 0; it < ROWS / 8; ++it) {
    int idx = t + 256 * it;
    int row = idx >> 5;
    int kq = idx & 31;
    int gr = r0 + row;
    float4 v = make_float4(0.f, 0.f, 0.f, 0.f);
    if (gr < R) v = *(const float4*)&X[(size_t)gr * 128 + kq * 4];
    *(float4*)&Xl[row][kq * 4] = v;
  }
  __syncthreads();
#pragma unroll
  for (int op = 0; op < NOPS; ++op) {
    if (p.o[op].chain != ch) continue;
    const float4* __restrict__ Wv = (const float4*)p.o[op].W;
    float acc[RPR][4];
#pragma unroll
    for (int i = 0; i < RPR; ++i)
#pragma unroll
      for (int j = 0; j < 4; ++j) acc[i][j] = 0.f;
#pragma unroll 2
    for (int k = 0; k < 128; k += 4) {
      float4 w0 = Wv[(k + 0) * 32 + tx];
      float4 w1 = Wv[(k + 1) * 32 + tx];
      float4 w2 = Wv[(k + 2) * 32 + tx];
      float4 w3 = Wv[(k + 3) * 32 + tx];
#pragma unroll
      for (int i = 0; i < RPR; ++i) {
        float4 xv = *(const float4*)&Xl[ty * RPR + i][k];
        acc[i][0] += xv.x * w0.x + xv.y * w1.x + xv.z * w2.x + xv.w * w3.x;
        acc[i][1] += xv.x * w0.y + xv.y * w1.y + xv.z * w2.y + xv.w * w3.y;
        acc[i][2] += xv.x * w0.z + xv.y * w1.z + xv.z * w2.z + xv.w * w3.z;
        acc[i][3] += xv.x * w0.w + xv.y * w1.w + xv.z * w2.w + xv.w * w3.w;
      }
    }
    float4 bv = make_float4(0.f, 0.f, 0.f, 0.f);
    if (p.o[op].bias) bv = *(const float4*)&p.o[op].bias[tx * 4];
    const bool relu = (p.o[op].flags & GF_RELU) != 0;
#pragma unroll
    for (int i = 0; i < RPR; ++i) {
      acc[i][0] += bv.x; acc[i][1] += bv.y; acc[i][2] += bv.z; acc[i][3] += bv.w;
      if (relu) {
#pragma unroll
        for (int c = 0; c < 4; ++c) acc[i][c] = fmaxf(acc[i][c], 0.f);
      }
    }
    if (p.o[op].flags & GF_TOLDS) {
      __syncthreads();  // all reads of old tile done
#pragma unroll
      for (int i = 0; i < RPR; ++i)
        *(float4*)&Xl[ty * RPR + i][tx * 4] =
            make_float4(acc[i][0], acc[i][1], acc[i][2], acc[i][3]);
      __syncthreads();
    } else {
      float* __restrict__ Y = p.o[op].Y;
#pragma unroll
      for (int i = 0; i < RPR; ++i) {
        int gr = r0 + ty * RPR + i;
        if (gr < R)
          *(float4*)&Y[(size_t)gr * 128 + tx * 4] =
              make_float4(acc[i][0], acc[i][1], acc[i][2], acc[i][3]);
      }
    }
  }
}

// ---------------- fused attention: score + top-k prune + compact + aggregate ----------------
// 256 threads = 4 waves; each wave owns one (batch,target). Per-wave LDS slices,
// wave lockstep orders phases (no __syncthreads).
template <int CAP>
__global__ __launch_bounds__(256) void attn_agg_k(
    const int* __restrict__ off, const int* __restrict__ bkt,
    const int* __restrict__ fidx, const float* __restrict__ ew,
    const float* __restrict__ Q, const float* __restrict__ K,
    const float* __restrict__ V, float* __restrict__ out,
    int nT, int nS, int topk) {
  __shared__ float s_sh[4][CAP];
  __shared__ int f_sh[4][CAP];
  __shared__ int e_sh[4][CAP];
  __shared__ int c_sh[4][CAP];
  __shared__ float q_sh[4][128];
  const int wv = threadIdx.x >> 6, lane = threadIdx.x & 63;
  const int t = blockIdx.x * 4 + wv, b = blockIdx.y;
  if (t >= nT) return;
  const int o0 = off[t];
  const int ne = min(off[t + 1] - o0, CAP);
  if (ne == 0) return;

  for (int i = lane; i < ne; i += 64) {
    int e = bkt[o0 + i];
    f_sh[wv][i] = fidx[e];
    e_sh[wv][i] = e;
    s_sh[wv][i] = ew[e];
  }
  *(float2*)&q_sh[wv][lane * 2] = *(const float2*)&Q[((size_t)b * nT + t) * 128 + lane * 2];

  // scores: 8 groups of 8 lanes -> 8 edges in flight
  const int g = lane >> 3, l = lane & 7;
  float4 q[4];
#pragma unroll
  for (int j = 0; j < 4; ++j) q[j] = *(const float4*)&q_sh[wv][(l + 8 * j) * 4];
  for (int i0 = 0; i0 < ne; i0 += 8) {
    int idx = i0 + g;
    bool val = idx < ne;
    int f = f_sh[wv][val ? idx : 0];
    const float4* kr = (const float4*)&K[((size_t)b * nS + f) * 128];
    float p = 0.f;
#pragma unroll
    for (int j = 0; j < 4; ++j) {
      float4 kv = kr[l + 8 * j];
      p += kv.x * q[j].x + kv.y * q[j].y + kv.z * q[j].z + kv.w * q[j].w;
    }
    p += __shfl_xor(p, 1);
    p += __shfl_xor(p, 2);
    p += __shfl_xor(p, 4);
    if (l == 0 && val) {
      float w = s_sh[wv][idx];  // edge weight (read before overwrite)
      s_sh[wv][idx] = 1.f / (1.f + expf(-p * RSQRTH_ * w));
    }
  }

  // prune: rank = #{j: s_j > s_i or (s_j == s_i and e_j < e_i)}
  float keep[(CAP + 63) / 64];
#pragma unroll
  for (int c = 0; c * 64 < CAP; ++c) {
    int i = lane + c * 64;
    float r = 0.f;
    if (i < ne) {
      float si = s_sh[wv][i];
      int ei = e_sh[wv][i];
      int cnt = 0;
      for (int j = 0; j < ne; ++j) {
        float sj = s_sh[wv][j];
        cnt += (sj > si) || (sj == si && e_sh[wv][j] < ei);
      }
      r = (cnt < topk && si > TAU_) ? si : 0.f;
    }
    keep[c] = r;
  }
#pragma unroll
  for (int c = 0; c * 64 < CAP; ++c) {
    int i = lane + c * 64;
    if (i < ne) s_sh[wv][i] = keep[c];
  }

  // ballot-compact selected edge slots
  int nsel = 0;
  for (int c = 0; c * 64 < ne; ++c) {
    int i = c * 64 + lane;
    bool sel = (i < ne) && (s_sh[wv][i] != 0.f);
    unsigned long long m = __ballot(sel);
    int pos = __popcll(m & ((1ull << lane) - 1ull));
    if (sel) c_sh[wv][nsel + pos] = i;
    nsel += __popcll(m);
  }

  // aggregate over compact list, 2x unrolled paired loads
  size_t orow = ((size_t)b * nT + t) * 128 + lane * 2;
  float2 acc = *(float2*)&out[orow];
  int j = 0;
  for (; j + 2 <= nsel; j += 2) {
    int i0 = c_sh[wv][j], i1 = c_sh[wv][j + 1];
    float w0 = s_sh[wv][i0], w1 = s_sh[wv][i1];
    float2 v0 = *(const float2*)&V[((size_t)b * nS + f_sh[wv][i0]) * 128 + lane * 2];
    float2 v1 = *(const float2*)&V[((size_t)b * nS + f_sh[wv][i1]) * 128 + lane * 2];
    acc.x += w0 * v0.x + w1 * v1.x;
    acc.y += w0 * v0.y + w1 * v1.y;
  }
  if (j < nsel) {
    int i0 = c_sh[wv][j];
    float w0 = s_sh[wv][i0];
    float2 v0 = *(const float2*)&V[((size_t)b * nS + f_sh[wv][i0]) * 128 + lane * 2];
    acc.x += w0 * v0.x;
    acc.y += w0 * v0.y;
  }
  *(float2*)&out[orow] = acc;
}

// ---------------- plain weighted aggregation (fixed edge weights) ----------------
template <int CAP>
__global__ __launch_bounds__(256) void wagg_k(
    const int* __restrict__ off, const int* __restrict__ bkt,
    const int* __restrict__ fidx, const float* __restrict__ ew,
    const float* __restrict__ V, float* __restrict__ out, int nT, int nS) {
  __shared__ float s_sh[4][CAP];
  __shared__ int f_sh[4][CAP];
  const int wv = threadIdx.x >> 6, lane = threadIdx.x & 63;
  const int t = blockIdx.x * 4 + wv, b = blockIdx.y;
  if (t >= nT) return;
  const int o0 = off[t];
  const int ne = min(off[t + 1] - o0, CAP);
  if (ne == 0) return;
  for (int i = lane; i < ne; i += 64) {
    int e = bkt[o0 + i];
    f_sh[wv][i] = fidx[e];
    s_sh[wv][i] = ew[e];
  }
  size_t orow = ((size_t)b * nT + t) * 128 + lane * 2;
  float2 acc = *(float2*)&out[orow];
  int i = 0;
  for (; i + 2 <= ne; i += 2) {
    float w0 = s_sh[wv][i], w1 = s_sh[wv][i + 1];
    float2 v0 = *(const float2*)&V[((size_t)b * nS + f_sh[wv][i]) * 128 + lane * 2];
    float2 v1 = *(const float2*)&V[((size_t)b * nS + f_sh[wv][i + 1]) * 128 + lane * 2];
    acc.x += w0 * v0.x + w1 * v1.x;
    acc.y += w0 * v0.y + w1 * v1.y;
  }
  if (i < ne) {
    float w0 = s_sh[wv][i];
    float2 v0 = *(const float2*)&V[((size_t)b * nS + f_sh[wv][i]) * 128 + lane * 2];
    acc.x += w0 * v0.x;
    acc.y += w0 * v0.y;
  }
  *(float2*)&out[orow] = acc;
}

// ---------------- host ----------------
extern "C" void kernel_launch(void* const* d_in, const int* in_sizes, int n_in, void* d_out,
                              int out_size, void* d_ws, size_t ws_size, hipStream_t stream) {
  const float* gene = (const float*)d_in[0];
  const float* path = (const float*)d_in[1];
  const float* gg_w = (const float*)d_in[2];
  const float* tg_w = (const float*)d_in[3];
  const float* gp_w = (const float*)d_in[4];
  const float* pp_w = (const float*)d_in[5];
  const int* gg_src = (const int*)d_in[6];
  const int* gg_dst = (const int*)d_in[7];
  const int* tg_src = (const int*)d_in[8];
  const int* tg_dst = (const int*)d_in[9];
  const int* gp_src = (const int*)d_in[10];
  const int* gp_dst = (const int*)d_in[11];
  const int* pp_src = (const int*)d_in[12];
  const int* pp_dst = (const int*)d_in[13];
  const float* mgg_w1 = (const float*)d_in[14];
  const float* mgg_b1 = (const float*)d_in[15];
  const float* mgg_w2 = (const float*)d_in[16];
  const float* mgg_b2 = (const float*)d_in[17];
  const float* mgp_w1 = (const float*)d_in[18];
  const float* mgp_b1 = (const float*)d_in[19];
  const float* mgp_w2 = (const float*)d_in[20];
  const float* mgp_b2 = (const float*)d_in[21];
  const float* mpp_w1 = (const float*)d_in[22];
  const float* mpp_b1 = (const float*)d_in[23];
  const float* mpp_w2 = (const float*)d_in[24];
  const float* mpp_b2 = (const float*)d_in[25];
  const float* mpg_w1 = (const float*)d_in[26];
  const float* mpg_b1 = (const float*)d_in[27];
  const float* mpg_w2 = (const float*)d_in[28];
  const float* mpg_b2 = (const float*)d_in[29];
  const float* w_gg = (const float*)d_in[30];
  const float* w_pp = (const float*)d_in[31];
  const float* w_pg = (const float*)d_in[32];
  const float* tg_q = (const float*)d_in[33];
  const float* tg_k = (const float*)d_in[34];
  const float* tg_v_tf = (const float*)d_in[35];
  const float* tg_v_gene = (const float*)d_in[36];
  const float* gp_q = (const float*)d_in[37];
  const float* gp_k = (const float*)d_in[38];
  const float* gp_v = (const float*)d_in[39];

  float* out_final = (float*)d_out;                       // [B,NG,H]
  float* out_h3 = (float*)d_out + (size_t)B_ * NG_ * H_;  // [B,NP,H]

  const size_t BNGH = (size_t)B_ * NG_ * H_;
  const size_t BNPH = (size_t)B_ * NP_ * H_;

  char* wp = (char*)d_ws;
  auto alloc = [&](size_t bytes) {
    void* p = (void*)wp;
    wp += (bytes + 255) & ~(size_t)255;
    return p;
  };
  float* G0 = (float*)alloc(BNGH * 4);  // h1
  float* G2 = (float*)alloc(BNGH * 4);  // Xw / q_gene / k_g
  float* G3 = (float*)alloc(BNGH * 4);  // k_tf / v_g
  float* G4 = (float*)alloc(BNGH * 4);  // v_tf
  float* G5 = (float*)alloc(BNGH * 4);  // h2
  float* P0 = (float*)alloc(BNPH * 4);  // q_p / Yw / Zw
  float* P2 = (float*)alloc(BNPH * 4);  // bar_h3
  const int NCNT = 3 * NG_ + 2 * NP_;
  int* cntbuf = (int*)alloc((size_t)NCNT * 2 * 4);
  int* cnt_gg = cntbuf;
  int* cnt_tg = cnt_gg + NG_;
  int* cnt_gps = cnt_tg + NG_;
  int* cnt_gpd = cnt_gps + NG_;
  int* cnt_pp = cnt_gpd + NP_;
  int* cur0 = cntbuf + NCNT;
  int* cur_gg = cur0;
  int* cur_tg = cur_gg + NG_;
  int* cur_gps = cur_tg + NG_;
  int* cur_gpd = cur_gps + NG_;
  int* cur_pp = cur_gpd + NP_;
  int* off_gg = (int*)alloc((size_t)(NG_ + 1) * 4);
  int* off_tg = (int*)alloc((size_t)(NG_ + 1) * 4);
  int* off_gps = (int*)alloc((size_t)(NG_ + 1) * 4);
  int* off_gpd = (int*)alloc((size_t)(NP_ + 1) * 4);
  int* off_pp = (int*)alloc((size_t)(NP_ + 1) * 4);
  int* bkt_gg = (int*)alloc((size_t)EGG_ * 4);
  int* bkt_tg = (int*)alloc((size_t)ETG_ * 4);
  int* bkt_gps = (int*)alloc((size_t)EGP_ * 4);
  int* bkt_gpd = (int*)alloc((size_t)EGP_ * 4);
  int* bkt_pp = (int*)alloc((size_t)EPP_ * 4);

  hipMemsetAsync(cntbuf, 0, (size_t)NCNT * 2 * 4, stream);
  CsrPack pk;
  pk.c[0] = {gg_dst, EGG_, NG_, cnt_gg, cur_gg, off_gg, bkt_gg};
  pk.c[1] = {tg_dst, ETG_, NG_, cnt_tg, cur_tg, off_tg, bkt_tg};
  pk.c[2] = {gp_src, EGP_, NG_, cnt_gps, cur_gps, off_gps, bkt_gps};
  pk.c[3] = {gp_dst, EGP_, NP_, cnt_gpd, cur_gpd, off_gpd, bkt_gpd};
  pk.c[4] = {pp_dst, EPP_, NP_, cnt_pp, cur_pp, off_pp, bkt_pp};
  hist_all_k<<<dim3((EGG_ + 255) / 256, 5), dim3(256), 0, stream>>>(pk);
  exscan_all_k<<<dim3(5), dim3(256), 0, stream>>>(pk);
  scatter_all_k<<<dim3((EGG_ + 255) / 256, 5), dim3(256), 0, stream>>>(pk);

  const int RG = B_ * NG_;  // 40000
  const int RP = B_ * NP_;  // 6000
  const int nbG = (RG + 31) / 32, nbP = (RP + 15) / 16;
  const dim3 blk(256);

  // ---- Layer 1: h1 = mlp_gg(gene) + scatter(gg_w * (gene@w_gg)[src]) ----
  {
    GPack p{};
    p.o[0] = {w_gg, nullptr, G2, 0, 0};
    p.o[1] = {mgg_w1, mgg_b1, nullptr, GF_RELU | GF_TOLDS, 1};
    p.o[2] = {mgg_w2, mgg_b2, G0, 0, 1};
    gemm_k<3, 32><<<dim3(nbG, 2), blk, 0, stream>>>(gene, p, RG);
  }
  wagg_k<128><<<dim3((NG_ + 3) / 4, B_), blk, 0, stream>>>(off_gg, bkt_gg, gg_src, gg_w, G2, G0,
                                                           NG_, NG_);
  // ---- Layer 2: TF->gene attention (4 independent projection chains) ----
  {
    GPack p{};
    p.o[0] = {tg_q, nullptr, G2, 0, 0};
    p.o[1] = {tg_k, nullptr, G3, 0, 1};
    p.o[2] = {tg_v_tf, nullptr, G4, 0, 2};
    p.o[3] = {tg_v_gene, nullptr, G5, 0, 3};
    gemm_k<4, 32><<<dim3(nbG, 4), blk, 0, stream>>>(G0, p, RG);
  }
  attn_agg_k<128><<<dim3((NG_ + 3) / 4, B_), blk, 0, stream>>>(
      off_tg, bkt_tg, tg_src, tg_w, G2, G3, G4, G5, NG_, NG_, 16);
  // ---- Layer 3 projections + Layer 5 MLP (both read G5) ----
  {
    GPack p{};
    p.o[0] = {gp_k, nullptr, G2, 0, 0};
    p.o[1] = {gp_v, nullptr, G3, 0, 1};
    p.o[2] = {mpg_w1, mpg_b1, nullptr, GF_RELU | GF_TOLDS, 2};
    p.o[3] = {mpg_w2, mpg_b2, out_final, 0, 2};  // final base; wagg adds later
    gemm_k<4, 32><<<dim3(nbG, 3), blk, 0, stream>>>(G5, p, RG);
  }
  {
    GPack p{};
    p.o[0] = {gp_q, nullptr, P0, 0, 0};
    p.o[1] = {mgp_w1, mgp_b1, nullptr, GF_RELU | GF_TOLDS, 1};
    p.o[2] = {mgp_w2, mgp_b2, P2, 0, 1};
    gemm_k<3, 16><<<dim3(nbP, 2), blk, 0, stream>>>(path, p, RP);
  }
  attn_agg_k<256><<<dim3((NP_ + 3) / 4, B_), blk, 0, stream>>>(
      off_gpd, bkt_gpd, gp_src, gp_w, P0, G2, G3, P2, NP_, NG_, 32);
  // ---- Layer 4: pathway-pathway ----
  {
    GPack p{};
    p.o[0] = {w_pp, nullptr, P0, 0, 0};
    p.o[1] = {mpp_w1, mpp_b1, nullptr, GF_RELU | GF_TOLDS, 1};
    p.o[2] = {mpp_w2, mpp_b2, out_h3, 0, 1};
    gemm_k<3, 16><<<dim3(nbP, 2), blk, 0, stream>>>(P2, p, RP);
  }
  wagg_k<192><<<dim3((NP_ + 3) / 4, B_), blk, 0, stream>>>(off_pp, bkt_pp, pp_src, pp_w, P0,
                                                           out_h3, NP_, NP_);
  // ---- Layer 5: pathway->gene feedback ----
  {
    GPack p{};
    p.o[0] = {w_pg, nullptr, P0, 0, 0};
    gemm_k<1, 16><<<dim3(nbP, 1), blk, 0, stream>>>(out_h3, p, RP);
  }
  wagg_k<128><<<dim3((NG_ + 3) / 4, B_), blk, 0, stream>>>(off_gps, bkt_gps, gp_dst, gp_w, P0,
                                                           out_final, NG_, NP_);
  (void)in_sizes; (void)n_in; (void)out_size; (void)ws_size;
}

// Round 8
// 818.598 us; speedup vs baseline: 1.2372x; 1.0262x over previous
//
#include <hip/hip_runtime.h>
#include <math.h>

#define H_ 128
static constexpr int NG_ = 20000, NP_ = 3000, B_ = 2;
static constexpr int EGG_ = 200000, ETG_ = 200000, EGP_ = 200000, EPP_ = 100000;
static constexpr float TAU_ = 0.5f;
static constexpr float RSQRTH_ = 0.088388347648318447f; // 1/sqrt(128)

// ---------------- batched CSR build ----------------
struct CsrDesc {
  const int* dst;
  int E, N;
  int* cnt;
  int* cur;
  int* off;
  int* bkt;
};
struct CsrPack { CsrDesc c[5]; };

__global__ void hist_all_k(CsrPack p) {
  CsrDesc d = p.c[blockIdx.y];
  int i = blockIdx.x * 256 + threadIdx.x;
  if (i < d.E) atomicAdd(&d.cnt[d.dst[i]], 1);
}

__global__ void scatter_all_k(CsrPack p) {
  CsrDesc d = p.c[blockIdx.y];
  int i = blockIdx.x * 256 + threadIdx.x;
  if (i < d.E) {
    int t = d.dst[i];
    int pos = atomicAdd(&d.cur[t], 1);
    d.bkt[d.off[t] + pos] = i;
  }
}

__global__ void exscan_all_k(CsrPack p) {
  CsrDesc d = p.c[blockIdx.x];
  const int n = d.N;
  const int* cnt = d.cnt;
  int* off = d.off;
  __shared__ int sh[256];
  const int tid = threadIdx.x;
  if (tid == 0) off[0] = 0;
  int run = 0;
  for (int base = 0; base < n; base += 4096) {
    int loc[16];
    int s = 0;
#pragma unroll
    for (int j = 0; j < 16; ++j) {
      int i = base + tid * 16 + j;
      loc[j] = (i < n) ? cnt[i] : 0;
      s += loc[j];
    }
    sh[tid] = s;
    __syncthreads();
    for (int st = 1; st < 256; st <<= 1) {
      int v = (tid >= st) ? sh[tid - st] : 0;
      __syncthreads();
      sh[tid] += v;
      __syncthreads();
    }
    int acc = run + ((tid > 0) ? sh[tid - 1] : 0);
    int tot = sh[255];
    __syncthreads();
#pragma unroll
    for (int j = 0; j < 16; ++j) {
      int i = base + tid * 16 + j;
      acc += loc[j];
      if (i < n) off[i + 1] = acc;
    }
    run += tot;
  }
}

// ---------------- W-stationary GEMM ----------------
// Full 128x128 W (64KB) staged in LDS per block -> inner loop has ZERO
// L2-latency-dependent loads for W (round 4/7 were W-latency bound: 64KB W
// thrashes 32KB L1, every load ~200cyc). X streamed from global via 8 row
// bases + immediate offsets (2 distinct 16B lines per wave load -> L1 hot).
// Register double-buffer of next chunk's W+X (VGPR budget 256 at 2 waves/SIMD,
// LDS caps at 2 blocks/CU). One op per blockIdx.y.
struct GOp { const float* W; const float* bias; float* Y; int relu; };
struct GPack { GOp o[4]; };

__global__ __launch_bounds__(256, 2) void gemmW_k(const float* __restrict__ X, GPack p, int R) {
  __shared__ float Wl[128 * 128];
  const GOp op = p.o[blockIdx.y];
  const int t = threadIdx.x;
  const int tx = t & 31, ty = t >> 5;
  {
    const float4* __restrict__ Wv = (const float4*)op.W;
    float4* Wlv = (float4*)Wl;
#pragma unroll
    for (int i = 0; i < 16; ++i) Wlv[t + 256 * i] = Wv[t + 256 * i];
  }
  __syncthreads();
  const int r0 = blockIdx.x * 64 + ty * 8;
  const float* xb[8];
#pragma unroll
  for (int i = 0; i < 8; ++i) {
    int gr = r0 + i;
    if (gr >= R) gr = R - 1;  // clamp loads; stores are guarded
    xb[i] = X + (size_t)gr * 128;
  }
  float acc[8][4];
#pragma unroll
  for (int i = 0; i < 8; ++i)
#pragma unroll
    for (int j = 0; j < 4; ++j) acc[i][j] = 0.f;

  float4 wc[4], xc[8];
#pragma unroll
  for (int j = 0; j < 4; ++j) wc[j] = *(const float4*)&Wl[j * 128 + tx * 4];
#pragma unroll
  for (int i = 0; i < 8; ++i) xc[i] = *(const float4*)(xb[i]);

  for (int k = 0; k < 128; k += 4) {
    float4 wn[4], xn[8];
    const int kn = (k + 4 < 128) ? (k + 4) : 0;  // wrap (dead on last iter)
#pragma unroll
    for (int j = 0; j < 4; ++j) wn[j] = *(const float4*)&Wl[(kn + j) * 128 + tx * 4];
#pragma unroll
    for (int i = 0; i < 8; ++i) xn[i] = *(const float4*)(xb[i] + kn);
#pragma unroll
    for (int i = 0; i < 8; ++i) {
      float4 xv = xc[i];
      acc[i][0] += xv.x * wc[0].x + xv.y * wc[1].x + xv.z * wc[2].x + xv.w * wc[3].x;
      acc[i][1] += xv.x * wc[0].y + xv.y * wc[1].y + xv.z * wc[2].y + xv.w * wc[3].y;
      acc[i][2] += xv.x * wc[0].z + xv.y * wc[1].z + xv.z * wc[2].z + xv.w * wc[3].z;
      acc[i][3] += xv.x * wc[0].w + xv.y * wc[1].w + xv.z * wc[2].w + xv.w * wc[3].w;
    }
#pragma unroll
    for (int j = 0; j < 4; ++j) wc[j] = wn[j];
#pragma unroll
    for (int i = 0; i < 8; ++i) xc[i] = xn[i];
  }
  float4 bv = make_float4(0.f, 0.f, 0.f, 0.f);
  if (op.bias) bv = *(const float4*)&op.bias[tx * 4];
  float* __restrict__ Y = op.Y;
#pragma unroll
  for (int i = 0; i < 8; ++i) {
    int gr = r0 + i;
    if (gr < R) {
      float4 o;
      o.x = acc[i][0] + bv.x; o.y = acc[i][1] + bv.y;
      o.z = acc[i][2] + bv.z; o.w = acc[i][3] + bv.w;
      if (op.relu) {
        o.x = fmaxf(o.x, 0.f); o.y = fmaxf(o.y, 0.f);
        o.z = fmaxf(o.z, 0.f); o.w = fmaxf(o.w, 0.f);
      }
      *(float4*)&Y[(size_t)gr * 128 + tx * 4] = o;
    }
  }
}

// ---------------- fused attention: score + top-k prune + compact + aggregate ----------------
template <int CAP>
__global__ __launch_bounds__(256) void attn_agg_k(
    const int* __restrict__ off, const int* __restrict__ bkt,
    const int* __restrict__ fidx, const float* __restrict__ ew,
    const float* __restrict__ Q, const float* __restrict__ K,
    const float* __restrict__ V, float* __restrict__ out,
    int nT, int nS, int topk) {
  __shared__ float s_sh[4][CAP];
  __shared__ int f_sh[4][CAP];
  __shared__ int e_sh[4][CAP];
  __shared__ int c_sh[4][CAP];
  __shared__ float q_sh[4][128];
  const int wv = threadIdx.x >> 6, lane = threadIdx.x & 63;
  const int t = blockIdx.x * 4 + wv, b = blockIdx.y;
  if (t >= nT) return;
  const int o0 = off[t];
  const int ne = min(off[t + 1] - o0, CAP);
  if (ne == 0) return;

  for (int i = lane; i < ne; i += 64) {
    int e = bkt[o0 + i];
    f_sh[wv][i] = fidx[e];
    e_sh[wv][i] = e;
    s_sh[wv][i] = ew[e];
  }
  *(float2*)&q_sh[wv][lane * 2] = *(const float2*)&Q[((size_t)b * nT + t) * 128 + lane * 2];

  const int g = lane >> 3, l = lane & 7;
  float4 q[4];
#pragma unroll
  for (int j = 0; j < 4; ++j) q[j] = *(const float4*)&q_sh[wv][(l + 8 * j) * 4];
  for (int i0 = 0; i0 < ne; i0 += 8) {
    int idx = i0 + g;
    bool val = idx < ne;
    int f = f_sh[wv][val ? idx : 0];
    const float4* kr = (const float4*)&K[((size_t)b * nS + f) * 128];
    float p = 0.f;
#pragma unroll
    for (int j = 0; j < 4; ++j) {
      float4 kv = kr[l + 8 * j];
      p += kv.x * q[j].x + kv.y * q[j].y + kv.z * q[j].z + kv.w * q[j].w;
    }
    p += __shfl_xor(p, 1);
    p += __shfl_xor(p, 2);
    p += __shfl_xor(p, 4);
    if (l == 0 && val) {
      float w = s_sh[wv][idx];
      s_sh[wv][idx] = 1.f / (1.f + expf(-p * RSQRTH_ * w));
    }
  }

  float keep[(CAP + 63) / 64];
#pragma unroll
  for (int c = 0; c * 64 < CAP; ++c) {
    int i = lane + c * 64;
    float r = 0.f;
    if (i < ne) {
      float si = s_sh[wv][i];
      int ei = e_sh[wv][i];
      int cnt = 0;
      for (int j = 0; j < ne; ++j) {
        float sj = s_sh[wv][j];
        cnt += (sj > si) || (sj == si && e_sh[wv][j] < ei);
      }
      r = (cnt < topk && si > TAU_) ? si : 0.f;
    }
    keep[c] = r;
  }
#pragma unroll
  for (int c = 0; c * 64 < CAP; ++c) {
    int i = lane + c * 64;
    if (i < ne) s_sh[wv][i] = keep[c];
  }

  int nsel = 0;
  for (int c = 0; c * 64 < ne; ++c) {
    int i = c * 64 + lane;
    bool sel = (i < ne) && (s_sh[wv][i] != 0.f);
    unsigned long long m = __ballot(sel);
    int pos = __popcll(m & ((1ull << lane) - 1ull));
    if (sel) c_sh[wv][nsel + pos] = i;
    nsel += __popcll(m);
  }

  size_t orow = ((size_t)b * nT + t) * 128 + lane * 2;
  float2 acc = *(float2*)&out[orow];
  int j = 0;
  for (; j + 2 <= nsel; j += 2) {
    int i0 = c_sh[wv][j], i1 = c_sh[wv][j + 1];
    float w0 = s_sh[wv][i0], w1 = s_sh[wv][i1];
    float2 v0 = *(const float2*)&V[((size_t)b * nS + f_sh[wv][i0]) * 128 + lane * 2];
    float2 v1 = *(const float2*)&V[((size_t)b * nS + f_sh[wv][i1]) * 128 + lane * 2];
    acc.x += w0 * v0.x + w1 * v1.x;
    acc.y += w0 * v0.y + w1 * v1.y;
  }
  if (j < nsel) {
    int i0 = c_sh[wv][j];
    float w0 = s_sh[wv][i0];
    float2 v0 = *(const float2*)&V[((size_t)b * nS + f_sh[wv][i0]) * 128 + lane * 2];
    acc.x += w0 * v0.x;
    acc.y += w0 * v0.y;
  }
  *(float2*)&out[orow] = acc;
}

// ---------------- plain weighted aggregation (fixed edge weights) ----------------
template <int CAP>
__global__ __launch_bounds__(256) void wagg_k(
    const int* __restrict__ off, const int* __restrict__ bkt,
    const int* __restrict__ fidx, const float* __restrict__ ew,
    const float* __restrict__ V, float* __restrict__ out, int nT, int nS) {
  __shared__ float s_sh[4][CAP];
  __shared__ int f_sh[4][CAP];
  const int wv = threadIdx.x >> 6, lane = threadIdx.x & 63;
  const int t = blockIdx.x * 4 + wv, b = blockIdx.y;
  if (t >= nT) return;
  const int o0 = off[t];
  const int ne = min(off[t + 1] - o0, CAP);
  if (ne == 0) return;
  for (int i = lane; i < ne; i += 64) {
    int e = bkt[o0 + i];
    f_sh[wv][i] = fidx[e];
    s_sh[wv][i] = ew[e];
  }
  size_t orow = ((size_t)b * nT + t) * 128 + lane * 2;
  float2 acc = *(float2*)&out[orow];
  int i = 0;
  for (; i + 2 <= ne; i += 2) {
    float w0 = s_sh[wv][i], w1 = s_sh[wv][i + 1];
    float2 v0 = *(const float2*)&V[((size_t)b * nS + f_sh[wv][i]) * 128 + lane * 2];
    float2 v1 = *(const float2*)&V[((size_t)b * nS + f_sh[wv][i + 1]) * 128 + lane * 2];
    acc.x += w0 * v0.x + w1 * v1.x;
    acc.y += w0 * v0.y + w1 * v1.y;
  }
  if (i < ne) {
    float w0 = s_sh[wv][i];
    float2 v0 = *(const float2*)&V[((size_t)b * nS + f_sh[wv][i]) * 128 + lane * 2];
    acc.x += w0 * v0.x;
    acc.y += w0 * v0.y;
  }
  *(float2*)&out[orow] = acc;
}

// ---------------- host ----------------
extern "C" void kernel_launch(void* const* d_in, const int* in_sizes, int n_in, void* d_out,
                              int out_size, void* d_ws, size_t ws_size, hipStream_t stream) {
  const float* gene = (const float*)d_in[0];
  const float* path = (const float*)d_in[1];
  const float* gg_w = (const float*)d_in[2];
  const float* tg_w = (const float*)d_in[3];
  const float* gp_w = (const float*)d_in[4];
  const float* pp_w = (const float*)d_in[5];
  const int* gg_src = (const int*)d_in[6];
  const int* gg_dst = (const int*)d_in[7];
  const int* tg_src = (const int*)d_in[8];
  const int* tg_dst = (const int*)d_in[9];
  const int* gp_src = (const int*)d_in[10];
  const int* gp_dst = (const int*)d_in[11];
  const int* pp_src = (const int*)d_in[12];
  const int* pp_dst = (const int*)d_in[13];
  const float* mgg_w1 = (const float*)d_in[14];
  const float* mgg_b1 = (const float*)d_in[15];
  const float* mgg_w2 = (const float*)d_in[16];
  const float* mgg_b2 = (const float*)d_in[17];
  const float* mgp_w1 = (const float*)d_in[18];
  const float* mgp_b1 = (const float*)d_in[19];
  const float* mgp_w2 = (const float*)d_in[20];
  const float* mgp_b2 = (const float*)d_in[21];
  const float* mpp_w1 = (const float*)d_in[22];
  const float* mpp_b1 = (const float*)d_in[23];
  const float* mpp_w2 = (const float*)d_in[24];
  const float* mpp_b2 = (const float*)d_in[25];
  const float* mpg_w1 = (const float*)d_in[26];
  const float* mpg_b1 = (const float*)d_in[27];
  const float* mpg_w2 = (const float*)d_in[28];
  const float* mpg_b2 = (const float*)d_in[29];
  const float* w_gg = (const float*)d_in[30];
  const float* w_pp = (const float*)d_in[31];
  const float* w_pg = (const float*)d_in[32];
  const float* tg_q = (const float*)d_in[33];
  const float* tg_k = (const float*)d_in[34];
  const float* tg_v_tf = (const float*)d_in[35];
  const float* tg_v_gene = (const float*)d_in[36];
  const float* gp_q = (const float*)d_in[37];
  const float* gp_k = (const float*)d_in[38];
  const float* gp_v = (const float*)d_in[39];

  float* out_final = (float*)d_out;                       // [B,NG,H]
  float* out_h3 = (float*)d_out + (size_t)B_ * NG_ * H_;  // [B,NP,H]

  const size_t BNGH = (size_t)B_ * NG_ * H_;
  const size_t BNPH = (size_t)B_ * NP_ * H_;

  char* wp = (char*)d_ws;
  auto alloc = [&](size_t bytes) {
    void* p = (void*)wp;
    wp += (bytes + 255) & ~(size_t)255;
    return p;
  };
  float* G0 = (float*)alloc(BNGH * 4);  // h1
  float* G1 = (float*)alloc(BNGH * 4);  // MLP hidden (gene-sized)
  float* G2 = (float*)alloc(BNGH * 4);  // Xw / q_gene / k_g
  float* G3 = (float*)alloc(BNGH * 4);  // k_tf / v_g
  float* G4 = (float*)alloc(BNGH * 4);  // v_tf
  float* G5 = (float*)alloc(BNGH * 4);  // h2
  float* P0 = (float*)alloc(BNPH * 4);  // q_p / Yw / Zw
  float* P1 = (float*)alloc(BNPH * 4);  // pathway MLP hidden
  float* P2 = (float*)alloc(BNPH * 4);  // bar_h3
  const int NCNT = 3 * NG_ + 2 * NP_;
  int* cntbuf = (int*)alloc((size_t)NCNT * 2 * 4);
  int* cnt_gg = cntbuf;
  int* cnt_tg = cnt_gg + NG_;
  int* cnt_gps = cnt_tg + NG_;
  int* cnt_gpd = cnt_gps + NG_;
  int* cnt_pp = cnt_gpd + NP_;
  int* cur0 = cntbuf + NCNT;
  int* cur_gg = cur0;
  int* cur_tg = cur_gg + NG_;
  int* cur_gps = cur_tg + NG_;
  int* cur_gpd = cur_gps + NG_;
  int* cur_pp = cur_gpd + NP_;
  int* off_gg = (int*)alloc((size_t)(NG_ + 1) * 4);
  int* off_tg = (int*)alloc((size_t)(NG_ + 1) * 4);
  int* off_gps = (int*)alloc((size_t)(NG_ + 1) * 4);
  int* off_gpd = (int*)alloc((size_t)(NP_ + 1) * 4);
  int* off_pp = (int*)alloc((size_t)(NP_ + 1) * 4);
  int* bkt_gg = (int*)alloc((size_t)EGG_ * 4);
  int* bkt_tg = (int*)alloc((size_t)ETG_ * 4);
  int* bkt_gps = (int*)alloc((size_t)EGP_ * 4);
  int* bkt_gpd = (int*)alloc((size_t)EGP_ * 4);
  int* bkt_pp = (int*)alloc((size_t)EPP_ * 4);

  hipMemsetAsync(cntbuf, 0, (size_t)NCNT * 2 * 4, stream);
  CsrPack pk;
  pk.c[0] = {gg_dst, EGG_, NG_, cnt_gg, cur_gg, off_gg, bkt_gg};
  pk.c[1] = {tg_dst, ETG_, NG_, cnt_tg, cur_tg, off_tg, bkt_tg};
  pk.c[2] = {gp_src, EGP_, NG_, cnt_gps, cur_gps, off_gps, bkt_gps};
  pk.c[3] = {gp_dst, EGP_, NP_, cnt_gpd, cur_gpd, off_gpd, bkt_gpd};
  pk.c[4] = {pp_dst, EPP_, NP_, cnt_pp, cur_pp, off_pp, bkt_pp};
  hist_all_k<<<dim3((EGG_ + 255) / 256, 5), dim3(256), 0, stream>>>(pk);
  exscan_all_k<<<dim3(5), dim3(256), 0, stream>>>(pk);
  scatter_all_k<<<dim3((EGG_ + 255) / 256, 5), dim3(256), 0, stream>>>(pk);

  const int RG = B_ * NG_;  // 40000 -> 625 row tiles exactly
  const int RP = B_ * NP_;  // 6000  -> 94 row tiles
  const int nbG = (RG + 63) / 64, nbP = (RP + 63) / 64;
  const dim3 blk(256);
  auto gemm = [&](const float* X, GPack& p, int nch, int R, int nb) {
    gemmW_k<<<dim3(nb, nch), blk, 0, stream>>>(X, p, R);
  };

  // ---- Layer 1 ----
  {
    GPack p{};
    p.o[0] = {w_gg, nullptr, G2, 0};
    p.o[1] = {mgg_w1, mgg_b1, G1, 1};
    gemm(gene, p, 2, RG, nbG);
  }
  {
    GPack p{};
    p.o[0] = {mgg_w2, mgg_b2, G0, 0};
    gemm(G1, p, 1, RG, nbG);
  }
  wagg_k<128><<<dim3((NG_ + 3) / 4, B_), blk, 0, stream>>>(off_gg, bkt_gg, gg_src, gg_w, G2, G0,
                                                           NG_, NG_);
  // ---- Layer 2: TF->gene attention ----
  {
    GPack p{};
    p.o[0] = {tg_q, nullptr, G2, 0};
    p.o[1] = {tg_k, nullptr, G3, 0};
    p.o[2] = {tg_v_tf, nullptr, G4, 0};
    p.o[3] = {tg_v_gene, nullptr, G5, 0};
    gemm(G0, p, 4, RG, nbG);
  }
  attn_agg_k<128><<<dim3((NG_ + 3) / 4, B_), blk, 0, stream>>>(
      off_tg, bkt_tg, tg_src, tg_w, G2, G3, G4, G5, NG_, NG_, 16);
  // ---- Layer 3 projections (+ layer-5 MLP hidden, all read G5/h2) ----
  {
    GPack p{};
    p.o[0] = {gp_k, nullptr, G2, 0};
    p.o[1] = {gp_v, nullptr, G3, 0};
    p.o[2] = {mpg_w1, mpg_b1, G1, 1};
    gemm(G5, p, 3, RG, nbG);
  }
  {
    GPack p{};
    p.o[0] = {mpg_w2, mpg_b2, out_final, 0};  // final base; wagg pg adds later
    gemm(G1, p, 1, RG, nbG);
  }
  {
    GPack p{};
    p.o[0] = {gp_q, nullptr, P0, 0};
    p.o[1] = {mgp_w1, mgp_b1, P1, 1};
    gemm(path, p, 2, RP, nbP);
  }
  {
    GPack p{};
    p.o[0] = {mgp_w2, mgp_b2, P2, 0};
    gemm(P1, p, 1, RP, nbP);
  }
  attn_agg_k<256><<<dim3((NP_ + 3) / 4, B_), blk, 0, stream>>>(
      off_gpd, bkt_gpd, gp_src, gp_w, P0, G2, G3, P2, NP_, NG_, 32);
  // ---- Layer 4: pathway-pathway ----
  {
    GPack p{};
    p.o[0] = {w_pp, nullptr, P0, 0};
    p.o[1] = {mpp_w1, mpp_b1, P1, 1};
    gemm(P2, p, 2, RP, nbP);
  }
  {
    GPack p{};
    p.o[0] = {mpp_w2, mpp_b2, out_h3, 0};
    gemm(P1, p, 1, RP, nbP);
  }
  wagg_k<192><<<dim3((NP_ + 3) / 4, B_), blk, 0, stream>>>(off_pp, bkt_pp, pp_src, pp_w, P0,
                                                           out_h3, NP_, NP_);
  // ---- Layer 5: pathway->gene feedback ----
  {
    GPack p{};
    p.o[0] = {w_pg, nullptr, P0, 0};
    gemm(out_h3, p, 1, RP, nbP);
  }
  wagg_k<128><<<dim3((NG_ + 3) / 4, B_), blk, 0, stream>>>(off_gps, bkt_gps, gp_dst, gp_w, P0,
                                                           out_final, NG_, NP_);
  (void)in_sizes; (void)n_in; (void)out_size; (void)ws_size;
}

// Round 9
// 807.670 us; speedup vs baseline: 1.2539x; 1.0135x over previous
//
#include <hip/hip_runtime.h>
#include <math.h>

#define H_ 128
static constexpr int NG_ = 20000, NP_ = 3000, B_ = 2;
static constexpr int EGG_ = 200000, ETG_ = 200000, EGP_ = 200000, EPP_ = 100000;
static constexpr float TAU_ = 0.5f;
static constexpr float RSQRTH_ = 0.088388347648318447f; // 1/sqrt(128)

// ---------------- batched CSR build ----------------
struct CsrDesc {
  const int* dst;
  int E, N;
  int* cnt;
  int* cur;
  int* off;
  int* bkt;
};
struct CsrPack { CsrDesc c[5]; };

__global__ void hist_all_k(CsrPack p) {
  CsrDesc d = p.c[blockIdx.y];
  int i = blockIdx.x * 256 + threadIdx.x;
  if (i < d.E) atomicAdd(&d.cnt[d.dst[i]], 1);
}

__global__ void scatter_all_k(CsrPack p) {
  CsrDesc d = p.c[blockIdx.y];
  int i = blockIdx.x * 256 + threadIdx.x;
  if (i < d.E) {
    int t = d.dst[i];
    int pos = atomicAdd(&d.cur[t], 1);
    d.bkt[d.off[t] + pos] = i;
  }
}

__global__ void exscan_all_k(CsrPack p) {
  CsrDesc d = p.c[blockIdx.x];
  const int n = d.N;
  const int* cnt = d.cnt;
  int* off = d.off;
  __shared__ int sh[256];
  const int tid = threadIdx.x;
  if (tid == 0) off[0] = 0;
  int run = 0;
  for (int base = 0; base < n; base += 4096) {
    int loc[16];
    int s = 0;
#pragma unroll
    for (int j = 0; j < 16; ++j) {
      int i = base + tid * 16 + j;
      loc[j] = (i < n) ? cnt[i] : 0;
      s += loc[j];
    }
    sh[tid] = s;
    __syncthreads();
    for (int st = 1; st < 256; st <<= 1) {
      int v = (tid >= st) ? sh[tid - st] : 0;
      __syncthreads();
      sh[tid] += v;
      __syncthreads();
    }
    int acc = run + ((tid > 0) ? sh[tid - 1] : 0);
    int tot = sh[255];
    __syncthreads();
#pragma unroll
    for (int j = 0; j < 16; ++j) {
      int i = base + tid * 16 + j;
      acc += loc[j];
      if (i < n) off[i + 1] = acc;
    }
    run += tot;
  }
}

// ---------------- W-stationary GEMM, 32KB k-half staging ----------------
// Round-8 lesson: 64KB W-in-LDS fixed the L1 thrash but capped occupancy at
// 2 blocks/CU (8 waves) -> VALU idle 48%. Staging W in TWO 32KB k-halves
// (acc carried across the barrier) keeps the same 128 FMA : 4 ds_read chunk
// mix while allowing 5 blocks/CU (~20 waves). No explicit register double
// buffer (round-5/8 lesson: costs movs + VGPR; TLP at 5 waves/SIMD hides
// ds_read and X-load latency). One op per blockIdx.y chain.
struct GOp { const float* W; const float* bias; float* Y; int relu; };
struct GPack { GOp o[4]; };

__global__ __launch_bounds__(256) void gemmW_k(const float* __restrict__ X, GPack p, int R) {
  __shared__ float Wl[64 * 128];  // 32 KB
  const GOp op = p.o[blockIdx.y];
  const int t = threadIdx.x;
  const int tx = t & 31, ty = t >> 5;
  const int r0 = blockIdx.x * 64 + ty * 8;
  const bool act = (r0 + 8 <= R);  // R % 8 == 0 for all our shapes
  const float* __restrict__ xrow = X + (size_t)(act ? r0 : 0) * 128;
  float acc[8][4];
#pragma unroll
  for (int i = 0; i < 8; ++i)
#pragma unroll
    for (int j = 0; j < 4; ++j) acc[i][j] = 0.f;

  for (int ks = 0; ks < 128; ks += 64) {
    {
      const float4* __restrict__ Wv = (const float4*)(op.W + ks * 128);
      float4* Wlv = (float4*)Wl;
#pragma unroll
      for (int i = 0; i < 8; ++i) Wlv[t + 256 * i] = Wv[t + 256 * i];
    }
    __syncthreads();
#pragma unroll 4
    for (int k = 0; k < 64; k += 4) {
      float4 w0 = *(const float4*)&Wl[(k + 0) * 128 + tx * 4];
      float4 w1 = *(const float4*)&Wl[(k + 1) * 128 + tx * 4];
      float4 w2 = *(const float4*)&Wl[(k + 2) * 128 + tx * 4];
      float4 w3 = *(const float4*)&Wl[(k + 3) * 128 + tx * 4];
#pragma unroll
      for (int i = 0; i < 8; ++i) {
        float4 xv = *(const float4*)(xrow + i * 128 + ks + k);
        acc[i][0] += xv.x * w0.x + xv.y * w1.x + xv.z * w2.x + xv.w * w3.x;
        acc[i][1] += xv.x * w0.y + xv.y * w1.y + xv.z * w2.y + xv.w * w3.y;
        acc[i][2] += xv.x * w0.z + xv.y * w1.z + xv.z * w2.z + xv.w * w3.z;
        acc[i][3] += xv.x * w0.w + xv.y * w1.w + xv.z * w2.w + xv.w * w3.w;
      }
    }
    __syncthreads();
  }
  float4 bv = make_float4(0.f, 0.f, 0.f, 0.f);
  if (op.bias) bv = *(const float4*)&op.bias[tx * 4];
  if (act) {
    float* __restrict__ Y = op.Y;
#pragma unroll
    for (int i = 0; i < 8; ++i) {
      float4 o;
      o.x = acc[i][0] + bv.x; o.y = acc[i][1] + bv.y;
      o.z = acc[i][2] + bv.z; o.w = acc[i][3] + bv.w;
      if (op.relu) {
        o.x = fmaxf(o.x, 0.f); o.y = fmaxf(o.y, 0.f);
        o.z = fmaxf(o.z, 0.f); o.w = fmaxf(o.w, 0.f);
      }
      *(float4*)&Y[(size_t)(r0 + i) * 128 + tx * 4] = o;
    }
  }
}

// ---------------- fused attention: score + top-k prune + compact + aggregate ----------------
template <int CAP>
__global__ __launch_bounds__(256) void attn_agg_k(
    const int* __restrict__ off, const int* __restrict__ bkt,
    const int* __restrict__ fidx, const float* __restrict__ ew,
    const float* __restrict__ Q, const float* __restrict__ K,
    const float* __restrict__ V, float* __restrict__ out,
    int nT, int nS, int topk) {
  __shared__ float s_sh[4][CAP];
  __shared__ int f_sh[4][CAP];
  __shared__ int e_sh[4][CAP];
  __shared__ int c_sh[4][CAP];
  __shared__ float q_sh[4][128];
  const int wv = threadIdx.x >> 6, lane = threadIdx.x & 63;
  const int t = blockIdx.x * 4 + wv, b = blockIdx.y;
  if (t >= nT) return;
  const int o0 = off[t];
  const int ne = min(off[t + 1] - o0, CAP);
  if (ne == 0) return;

  for (int i = lane; i < ne; i += 64) {
    int e = bkt[o0 + i];
    f_sh[wv][i] = fidx[e];
    e_sh[wv][i] = e;
    s_sh[wv][i] = ew[e];
  }
  *(float2*)&q_sh[wv][lane * 2] = *(const float2*)&Q[((size_t)b * nT + t) * 128 + lane * 2];

  const int g = lane >> 3, l = lane & 7;
  float4 q[4];
#pragma unroll
  for (int j = 0; j < 4; ++j) q[j] = *(const float4*)&q_sh[wv][(l + 8 * j) * 4];
  for (int i0 = 0; i0 < ne; i0 += 8) {
    int idx = i0 + g;
    bool val = idx < ne;
    int f = f_sh[wv][val ? idx : 0];
    const float4* kr = (const float4*)&K[((size_t)b * nS + f) * 128];
    float p = 0.f;
#pragma unroll
    for (int j = 0; j < 4; ++j) {
      float4 kv = kr[l + 8 * j];
      p += kv.x * q[j].x + kv.y * q[j].y + kv.z * q[j].z + kv.w * q[j].w;
    }
    p += __shfl_xor(p, 1);
    p += __shfl_xor(p, 2);
    p += __shfl_xor(p, 4);
    if (l == 0 && val) {
      float w = s_sh[wv][idx];
      s_sh[wv][idx] = 1.f / (1.f + expf(-p * RSQRTH_ * w));
    }
  }

  float keep[(CAP + 63) / 64];
#pragma unroll
  for (int c = 0; c * 64 < CAP; ++c) {
    int i = lane + c * 64;
    float r = 0.f;
    if (i < ne) {
      float si = s_sh[wv][i];
      int ei = e_sh[wv][i];
      int cnt = 0;
      for (int j = 0; j < ne; ++j) {
        float sj = s_sh[wv][j];
        cnt += (sj > si) || (sj == si && e_sh[wv][j] < ei);
      }
      r = (cnt < topk && si > TAU_) ? si : 0.f;
    }
    keep[c] = r;
  }
#pragma unroll
  for (int c = 0; c * 64 < CAP; ++c) {
    int i = lane + c * 64;
    if (i < ne) s_sh[wv][i] = keep[c];
  }

  int nsel = 0;
  for (int c = 0; c * 64 < ne; ++c) {
    int i = c * 64 + lane;
    bool sel = (i < ne) && (s_sh[wv][i] != 0.f);
    unsigned long long m = __ballot(sel);
    int pos = __popcll(m & ((1ull << lane) - 1ull));
    if (sel) c_sh[wv][nsel + pos] = i;
    nsel += __popcll(m);
  }

  size_t orow = ((size_t)b * nT + t) * 128 + lane * 2;
  float2 acc = *(float2*)&out[orow];
  int j = 0;
  for (; j + 2 <= nsel; j += 2) {
    int i0 = c_sh[wv][j], i1 = c_sh[wv][j + 1];
    float w0 = s_sh[wv][i0], w1 = s_sh[wv][i1];
    float2 v0 = *(const float2*)&V[((size_t)b * nS + f_sh[wv][i0]) * 128 + lane * 2];
    float2 v1 = *(const float2*)&V[((size_t)b * nS + f_sh[wv][i1]) * 128 + lane * 2];
    acc.x += w0 * v0.x + w1 * v1.x;
    acc.y += w0 * v0.y + w1 * v1.y;
  }
  if (j < nsel) {
    int i0 = c_sh[wv][j];
    float w0 = s_sh[wv][i0];
    float2 v0 = *(const float2*)&V[((size_t)b * nS + f_sh[wv][i0]) * 128 + lane * 2];
    acc.x += w0 * v0.x;
    acc.y += w0 * v0.y;
  }
  *(float2*)&out[orow] = acc;
}

// ---------------- plain weighted aggregation (fixed edge weights) ----------------
template <int CAP>
__global__ __launch_bounds__(256) void wagg_k(
    const int* __restrict__ off, const int* __restrict__ bkt,
    const int* __restrict__ fidx, const float* __restrict__ ew,
    const float* __restrict__ V, float* __restrict__ out, int nT, int nS) {
  __shared__ float s_sh[4][CAP];
  __shared__ int f_sh[4][CAP];
  const int wv = threadIdx.x >> 6, lane = threadIdx.x & 63;
  const int t = blockIdx.x * 4 + wv, b = blockIdx.y;
  if (t >= nT) return;
  const int o0 = off[t];
  const int ne = min(off[t + 1] - o0, CAP);
  if (ne == 0) return;
  for (int i = lane; i < ne; i += 64) {
    int e = bkt[o0 + i];
    f_sh[wv][i] = fidx[e];
    s_sh[wv][i] = ew[e];
  }
  size_t orow = ((size_t)b * nT + t) * 128 + lane * 2;
  float2 acc = *(float2*)&out[orow];
  int i = 0;
  for (; i + 2 <= ne; i += 2) {
    float w0 = s_sh[wv][i], w1 = s_sh[wv][i + 1];
    float2 v0 = *(const float2*)&V[((size_t)b * nS + f_sh[wv][i]) * 128 + lane * 2];
    float2 v1 = *(const float2*)&V[((size_t)b * nS + f_sh[wv][i + 1]) * 128 + lane * 2];
    acc.x += w0 * v0.x + w1 * v1.x;
    acc.y += w0 * v0.y + w1 * v1.y;
  }
  if (i < ne) {
    float w0 = s_sh[wv][i];
    float2 v0 = *(const float2*)&V[((size_t)b * nS + f_sh[wv][i]) * 128 + lane * 2];
    acc.x += w0 * v0.x;
    acc.y += w0 * v0.y;
  }
  *(float2*)&out[orow] = acc;
}

// ---------------- host ----------------
extern "C" void kernel_launch(void* const* d_in, const int* in_sizes, int n_in, void* d_out,
                              int out_size, void* d_ws, size_t ws_size, hipStream_t stream) {
  const float* gene = (const float*)d_in[0];
  const float* path = (const float*)d_in[1];
  const float* gg_w = (const float*)d_in[2];
  const float* tg_w = (const float*)d_in[3];
  const float* gp_w = (const float*)d_in[4];
  const float* pp_w = (const float*)d_in[5];
  const int* gg_src = (const int*)d_in[6];
  const int* gg_dst = (const int*)d_in[7];
  const int* tg_src = (const int*)d_in[8];
  const int* tg_dst = (const int*)d_in[9];
  const int* gp_src = (const int*)d_in[10];
  const int* gp_dst = (const int*)d_in[11];
  const int* pp_src = (const int*)d_in[12];
  const int* pp_dst = (const int*)d_in[13];
  const float* mgg_w1 = (const float*)d_in[14];
  const float* mgg_b1 = (const float*)d_in[15];
  const float* mgg_w2 = (const float*)d_in[16];
  const float* mgg_b2 = (const float*)d_in[17];
  const float* mgp_w1 = (const float*)d_in[18];
  const float* mgp_b1 = (const float*)d_in[19];
  const float* mgp_w2 = (const float*)d_in[20];
  const float* mgp_b2 = (const float*)d_in[21];
  const float* mpp_w1 = (const float*)d_in[22];
  const float* mpp_b1 = (const float*)d_in[23];
  const float* mpp_w2 = (const float*)d_in[24];
  const float* mpp_b2 = (const float*)d_in[25];
  const float* mpg_w1 = (const float*)d_in[26];
  const float* mpg_b1 = (const float*)d_in[27];
  const float* mpg_w2 = (const float*)d_in[28];
  const float* mpg_b2 = (const float*)d_in[29];
  const float* w_gg = (const float*)d_in[30];
  const float* w_pp = (const float*)d_in[31];
  const float* w_pg = (const float*)d_in[32];
  const float* tg_q = (const float*)d_in[33];
  const float* tg_k = (const float*)d_in[34];
  const float* tg_v_tf = (const float*)d_in[35];
  const float* tg_v_gene = (const float*)d_in[36];
  const float* gp_q = (const float*)d_in[37];
  const float* gp_k = (const float*)d_in[38];
  const float* gp_v = (const float*)d_in[39];

  float* out_final = (float*)d_out;                       // [B,NG,H]
  float* out_h3 = (float*)d_out + (size_t)B_ * NG_ * H_;  // [B,NP,H]

  const size_t BNGH = (size_t)B_ * NG_ * H_;
  const size_t BNPH = (size_t)B_ * NP_ * H_;

  char* wp = (char*)d_ws;
  auto alloc = [&](size_t bytes) {
    void* p = (void*)wp;
    wp += (bytes + 255) & ~(size_t)255;
    return p;
  };
  float* G0 = (float*)alloc(BNGH * 4);  // h1
  float* G1 = (float*)alloc(BNGH * 4);  // MLP hidden (gene-sized)
  float* G2 = (float*)alloc(BNGH * 4);  // Xw / q_gene / k_g
  float* G3 = (float*)alloc(BNGH * 4);  // k_tf / v_g
  float* G4 = (float*)alloc(BNGH * 4);  // v_tf
  float* G5 = (float*)alloc(BNGH * 4);  // h2
  float* P0 = (float*)alloc(BNPH * 4);  // q_p / Yw / Zw
  float* P1 = (float*)alloc(BNPH * 4);  // pathway MLP hidden
  float* P2 = (float*)alloc(BNPH * 4);  // bar_h3
  const int NCNT = 3 * NG_ + 2 * NP_;
  int* cntbuf = (int*)alloc((size_t)NCNT * 2 * 4);
  int* cnt_gg = cntbuf;
  int* cnt_tg = cnt_gg + NG_;
  int* cnt_gps = cnt_tg + NG_;
  int* cnt_gpd = cnt_gps + NG_;
  int* cnt_pp = cnt_gpd + NP_;
  int* cur0 = cntbuf + NCNT;
  int* cur_gg = cur0;
  int* cur_tg = cur_gg + NG_;
  int* cur_gps = cur_tg + NG_;
  int* cur_gpd = cur_gps + NG_;
  int* cur_pp = cur_gpd + NP_;
  int* off_gg = (int*)alloc((size_t)(NG_ + 1) * 4);
  int* off_tg = (int*)alloc((size_t)(NG_ + 1) * 4);
  int* off_gps = (int*)alloc((size_t)(NG_ + 1) * 4);
  int* off_gpd = (int*)alloc((size_t)(NP_ + 1) * 4);
  int* off_pp = (int*)alloc((size_t)(NP_ + 1) * 4);
  int* bkt_gg = (int*)alloc((size_t)EGG_ * 4);
  int* bkt_tg = (int*)alloc((size_t)ETG_ * 4);
  int* bkt_gps = (int*)alloc((size_t)EGP_ * 4);
  int* bkt_gpd = (int*)alloc((size_t)EGP_ * 4);
  int* bkt_pp = (int*)alloc((size_t)EPP_ * 4);

  hipMemsetAsync(cntbuf, 0, (size_t)NCNT * 2 * 4, stream);
  CsrPack pk;
  pk.c[0] = {gg_dst, EGG_, NG_, cnt_gg, cur_gg, off_gg, bkt_gg};
  pk.c[1] = {tg_dst, ETG_, NG_, cnt_tg, cur_tg, off_tg, bkt_tg};
  pk.c[2] = {gp_src, EGP_, NG_, cnt_gps, cur_gps, off_gps, bkt_gps};
  pk.c[3] = {gp_dst, EGP_, NP_, cnt_gpd, cur_gpd, off_gpd, bkt_gpd};
  pk.c[4] = {pp_dst, EPP_, NP_, cnt_pp, cur_pp, off_pp, bkt_pp};
  hist_all_k<<<dim3((EGG_ + 255) / 256, 5), dim3(256), 0, stream>>>(pk);
  exscan_all_k<<<dim3(5), dim3(256), 0, stream>>>(pk);
  scatter_all_k<<<dim3((EGG_ + 255) / 256, 5), dim3(256), 0, stream>>>(pk);

  const int RG = B_ * NG_;  // 40000 -> 625 row tiles exactly
  const int RP = B_ * NP_;  // 6000  -> 94 row tiles
  const int nbG = (RG + 63) / 64, nbP = (RP + 63) / 64;
  const dim3 blk(256);
  auto gemm = [&](const float* X, GPack& p, int nch, int R, int nb) {
    gemmW_k<<<dim3(nb, nch), blk, 0, stream>>>(X, p, R);
  };

  // ---- Layer 1 ----
  {
    GPack p{};
    p.o[0] = {w_gg, nullptr, G2, 0};
    p.o[1] = {mgg_w1, mgg_b1, G1, 1};
    gemm(gene, p, 2, RG, nbG);
  }
  {
    GPack p{};
    p.o[0] = {mgg_w2, mgg_b2, G0, 0};
    gemm(G1, p, 1, RG, nbG);
  }
  wagg_k<128><<<dim3((NG_ + 3) / 4, B_), blk, 0, stream>>>(off_gg, bkt_gg, gg_src, gg_w, G2, G0,
                                                           NG_, NG_);
  // ---- Layer 2: TF->gene attention ----
  {
    GPack p{};
    p.o[0] = {tg_q, nullptr, G2, 0};
    p.o[1] = {tg_k, nullptr, G3, 0};
    p.o[2] = {tg_v_tf, nullptr, G4, 0};
    p.o[3] = {tg_v_gene, nullptr, G5, 0};
    gemm(G0, p, 4, RG, nbG);
  }
  attn_agg_k<128><<<dim3((NG_ + 3) / 4, B_), blk, 0, stream>>>(
      off_tg, bkt_tg, tg_src, tg_w, G2, G3, G4, G5, NG_, NG_, 16);
  // ---- Layer 3 projections (+ layer-5 MLP hidden, all read G5/h2) ----
  {
    GPack p{};
    p.o[0] = {gp_k, nullptr, G2, 0};
    p.o[1] = {gp_v, nullptr, G3, 0};
    p.o[2] = {mpg_w1, mpg_b1, G1, 1};
    gemm(G5, p, 3, RG, nbG);
  }
  {
    GPack p{};
    p.o[0] = {mpg_w2, mpg_b2, out_final, 0};  // final base; wagg pg adds later
    gemm(G1, p, 1, RG, nbG);
  }
  {
    GPack p{};
    p.o[0] = {gp_q, nullptr, P0, 0};
    p.o[1] = {mgp_w1, mgp_b1, P1, 1};
    gemm(path, p, 2, RP, nbP);
  }
  {
    GPack p{};
    p.o[0] = {mgp_w2, mgp_b2, P2, 0};
    gemm(P1, p, 1, RP, nbP);
  }
  attn_agg_k<256><<<dim3((NP_ + 3) / 4, B_), blk, 0, stream>>>(
      off_gpd, bkt_gpd, gp_src, gp_w, P0, G2, G3, P2, NP_, NG_, 32);
  // ---- Layer 4: pathway-pathway ----
  {
    GPack p{};
    p.o[0] = {w_pp, nullptr, P0, 0};
    p.o[1] = {mpp_w1, mpp_b1, P1, 1};
    gemm(P2, p, 2, RP, nbP);
  }
  {
    GPack p{};
    p.o[0] = {mpp_w2, mpp_b2, out_h3, 0};
    gemm(P1, p, 1, RP, nbP);
  }
  wagg_k<192><<<dim3((NP_ + 3) / 4, B_), blk, 0, stream>>>(off_pp, bkt_pp, pp_src, pp_w, P0,
                                                           out_h3, NP_, NP_);
  // ---- Layer 5: pathway->gene feedback ----
  {
    GPack p{};
    p.o[0] = {w_pg, nullptr, P0, 0};
    gemm(out_h3, p, 1, RP, nbP);
  }
  wagg_k<128><<<dim3((NG_ + 3) / 4, B_), blk, 0, stream>>>(off_gps, bkt_gps, gp_dst, gp_w, P0,
                                                           out_final, NG_, NP_);
  (void)in_sizes; (void)n_in; (void)out_size; (void)ws_size;
}